// Round 6
// baseline (282.470 us; speedup 1.0000x reference)
//
#include <hip/hip_runtime.h>
#include <hip/hip_bf16.h>

#define L_ROWS 16384
#define D_COLS 2048
#define NB 32                    // thresholds; bins over [-4,4], w = 0.25
#define ROWS_PER_BLOCK 4         // one wave per row
#define THREADS 256
#define NBLOCKS (L_ROWS / ROWS_PER_BLOCK)

// Thermometer mask: bit k set iff bin(x) <= k, i.e. x below edge e_k.
// One mask = all 32 threshold comparisons for this sample.
__device__ __forceinline__ unsigned therm(float x) {
    float t = fminf(fmaxf(fmaf(x, 4.0f, 16.0f), 0.0f), 31.0f);
    return 0xFFFFFFFFu << (int)t;
}

// bit-plane full adder: {s,cout} = a + b + cin per bit position
__device__ __forceinline__ void fa(unsigned& s, unsigned a, unsigned b,
                                   unsigned cin, unsigned& cout) {
    unsigned x = a ^ b;
    s = x ^ cin;
    cout = (a & b) | (cin & x);
}

// 6-deep bit-sliced counter bank: 32 independent counters (one per threshold),
// counts <= 32. Adds 4 one-bit masks per call via a small CSA tree.
struct Sliced {
    unsigned c[6];
    __device__ __forceinline__ void init() {
#pragma unroll
        for (int d = 0; d < 6; ++d) c[d] = 0u;
    }
    __device__ __forceinline__ void add4(unsigned m0, unsigned m1,
                                         unsigned m2, unsigned m3) {
        // FA(m0,m1,m2) -> t0 (w1), t1 (w2)
        unsigned t0, t1;
        { unsigned x = m0 ^ m1; t0 = x ^ m2; t1 = (m0 & m1) | (m2 & x); }
        // + m3: HA at w1, then HA at w2 -> t2 (w4)
        unsigned c1 = t0 & m3; t0 ^= m3;
        unsigned t2 = t1 & c1; t1 ^= c1;
        // flush (t2,t1,t0) into c[0..5]
        unsigned cy = c[0] & t0; c[0] ^= t0;               // L0: HA
        { unsigned s1; fa(s1, c[1], t1, cy, cy); c[1] = s1; }  // L1: FA
        { unsigned s2; fa(s2, c[2], t2, cy, cy); c[2] = s2; }  // L2: FA
        unsigned nt;
        nt = c[3] & cy; c[3] ^= cy; cy = nt;               // L3 ripple
        nt = c[4] & cy; c[4] ^= cy; cy = nt;               // L4 ripple
        c[5] ^= cy;                                        // L5 (max 32 fits)
    }
};

__global__ __launch_bounds__(THREADS, 8) void w1_csa_kernel(
    const float* __restrict__ z2, const float* __restrict__ z1,
    unsigned int* __restrict__ partial)
{
    __shared__ int wpart[ROWS_PER_BLOCK];

    const int lane = threadIdx.x & 63;
    const int wid  = threadIdx.x >> 6;
    const int row  = blockIdx.x * ROWS_PER_BLOCK + wid;

    const float4* pa = (const float4*)(z2 + (size_t)row * D_COLS);
    const float4* pb = (const float4*)(z1 + (size_t)row * D_COLS);

    Sliced A, B;
    A.init(); B.init();

    // Two halves: stage 8 float4 (4 KB/wave in flight), then CSA them.
    // Sample->lane partition is arbitrary for counting, so use fully
    // coalesced loads (lane i takes float4 #(u*64+i)).
#pragma unroll
    for (int h = 0; h < 2; ++h) {
        float4 ra[4], rb[4];
#pragma unroll
        for (int u = 0; u < 4; ++u) ra[u] = pa[(h * 4 + u) * 64 + lane];
#pragma unroll
        for (int u = 0; u < 4; ++u) rb[u] = pb[(h * 4 + u) * 64 + lane];
#pragma unroll
        for (int u = 0; u < 4; ++u)
            A.add4(therm(ra[u].x), therm(ra[u].y), therm(ra[u].z), therm(ra[u].w));
#pragma unroll
        for (int u = 0; u < 4; ++u)
            B.add4(therm(rb[u].x), therm(rb[u].y), therm(rb[u].z), therm(rb[u].w));
    }

    // Cross-lane reduction in the bit-sliced domain: butterfly over 64 lanes,
    // width grows 6 -> 12 (row totals <= 2048 = 2^11).
    unsigned sA[12], sB[12];
#pragma unroll
    for (int d = 0; d < 12; ++d) {
        sA[d] = (d < 6) ? A.c[d] : 0u;
        sB[d] = (d < 6) ? B.c[d] : 0u;
    }
#pragma unroll
    for (int i = 0; i < 6; ++i) {
        const int step = 1 << i;
        const int W = 6 + i;             // current width; result width W+1
        unsigned cy = 0u;
#pragma unroll
        for (int d = 0; d < 12; ++d) {
            if (d < W) {
                unsigned p = (unsigned)__shfl_xor((int)sA[d], step, 64);
                unsigned s; fa(s, sA[d], p, cy, cy); sA[d] = s;
            }
        }
        sA[W] = cy;
        cy = 0u;
#pragma unroll
        for (int d = 0; d < 12; ++d) {
            if (d < W) {
                unsigned p = (unsigned)__shfl_xor((int)sB[d], step, 64);
                unsigned s; fa(s, sB[d], p, cy, cy); sB[d] = s;
            }
        }
        sB[W] = cy;
    }

    // Every lane now holds the full row's sliced counts. Lane t (t<32)
    // extracts threshold t, takes |cumA - cumB|; integer-exact.
    const int t = lane & 31;
    int cA = 0, cB = 0;
#pragma unroll
    for (int d = 0; d < 12; ++d) {
        cA += (int)((sA[d] >> t) & 1u) << d;
        cB += (int)((sB[d] >> t) & 1u) << d;
    }
    int diff = cA - cB;
    int contrib = (lane < 32) ? ((diff < 0) ? -diff : diff) : 0;

#pragma unroll
    for (int off = 32; off > 0; off >>= 1)
        contrib += __shfl_xor(contrib, off, 64);

    if (lane == 0) wpart[wid] = contrib;
    __syncthreads();
    if (threadIdx.x == 0)
        partial[blockIdx.x] = (unsigned int)(wpart[0] + wpart[1] + wpart[2] + wpart[3]);
}

__global__ __launch_bounds__(256) void w1_reduce_kernel(
    const unsigned int* __restrict__ partial, float* __restrict__ out)
{
    unsigned int s = 0;
    for (int i = threadIdx.x; i < NBLOCKS; i += 256)
        s += partial[i];

#pragma unroll
    for (int off = 32; off > 0; off >>= 1)
        s += __shfl_xor(s, off, 64);

    __shared__ unsigned int ws[4];
    const int lane = threadIdx.x & 63;
    const int wid  = threadIdx.x >> 6;
    if (lane == 0) ws[wid] = s;
    __syncthreads();

    if (threadIdx.x == 0) {
        double tot = (double)(ws[0] + ws[1] + ws[2] + ws[3]);
        // W1 = w * sum|cum| / n, averaged over rows; w = 0.25
        double w = tot * 0.25 / ((double)D_COLS * (double)L_ROWS);
        out[0] = (float)(1.0 - w);
    }
}

extern "C" void kernel_launch(void* const* d_in, const int* in_sizes, int n_in,
                              void* d_out, int out_size, void* d_ws, size_t ws_size,
                              hipStream_t stream) {
    const float* z2 = (const float*)d_in[0];
    const float* z1 = (const float*)d_in[1];
    float* out = (float*)d_out;
    unsigned int* partial = (unsigned int*)d_ws;   // NBLOCKS uints, all written

    w1_csa_kernel<<<NBLOCKS, THREADS, 0, stream>>>(z2, z1, partial);
    w1_reduce_kernel<<<1, 256, 0, stream>>>(partial, out);
}